// Round 12
// baseline (359.851 us; speedup 1.0000x reference)
//
#include <hip/hip_runtime.h>

#define NN 100000
#define EE 500000
#define DD 64
#define OD 16
#define NR 6
#define NBASE 4
#define BSH 10
#define NBK 98         /* ceil(NN / 1024) */
#define SBLK 128       /* scatter blocks per relation */
#define FLATN (NBK * SBLK)   /* 12544 */
#define STCAP 5632     /* fine-bucket edge capacity */
#define DBIN 64        /* degree-sort bins */
#define LROW 100       /* LDS row stride in dwords (padded, 16B-aligned) */

struct Edges { const int* src[NR]; const int* dst[NR]; };

typedef __attribute__((ext_vector_type(8))) short bf16x8;
typedef __attribute__((ext_vector_type(4))) float f32x4;

__device__ __forceinline__ float bf2f(ushort u) {
    union { unsigned int i; float f; } v; v.i = ((unsigned int)u) << 16; return v.f;
}
__device__ __forceinline__ ushort f2bf(float f) {
    unsigned int x = __float_as_uint(f);
    unsigned int r = (x + 0x7fffu + ((x >> 16) & 1u)) >> 16;
    return (ushort)r;
}
__device__ __forceinline__ void bfpair(unsigned int u, float& lo, float& hi) {
    lo = __uint_as_float(u << 16);
    hi = __uint_as_float(u & 0xffff0000u);
}

// gather-sum rows [s,e) of F (bf16, permuted index space) into a[8] for dim slice sub
__device__ __forceinline__ void gather8(
    const ushort* __restrict__ F, const int* __restrict__ ci,
    int s, int e, int sub, float* a)
{
    int t = s;
    for (; t + 2 <= e; t += 2) {
        int c0 = ci[t], c1 = ci[t + 1];
        int4 u = *(const int4*)(F + (size_t)c0 * DD + sub * 8);
        int4 w = *(const int4*)(F + (size_t)c1 * DD + sub * 8);
        float l, h;
        bfpair((unsigned int)u.x, l, h); a[0] += l; a[1] += h;
        bfpair((unsigned int)u.y, l, h); a[2] += l; a[3] += h;
        bfpair((unsigned int)u.z, l, h); a[4] += l; a[5] += h;
        bfpair((unsigned int)u.w, l, h); a[6] += l; a[7] += h;
        bfpair((unsigned int)w.x, l, h); a[0] += l; a[1] += h;
        bfpair((unsigned int)w.y, l, h); a[2] += l; a[3] += h;
        bfpair((unsigned int)w.z, l, h); a[4] += l; a[5] += h;
        bfpair((unsigned int)w.w, l, h); a[6] += l; a[7] += h;
    }
    if (t < e) {
        int4 u = *(const int4*)(F + (size_t)ci[t] * DD + sub * 8);
        float l, h;
        bfpair((unsigned int)u.x, l, h); a[0] += l; a[1] += h;
        bfpair((unsigned int)u.y, l, h); a[2] += l; a[3] += h;
        bfpair((unsigned int)u.z, l, h); a[4] += l; a[5] += h;
        bfpair((unsigned int)u.w, l, h); a[6] += l; a[7] += h;
    }
}

// ---------------- W = einsum('rb,bio->rio'), emitted bf16 B-fragment-packed ----------------
__global__ __launch_bounds__(256) void build_w_kernel(
    const float* __restrict__ wc1, const float* __restrict__ b1,
    const float* __restrict__ wc2, const float* __restrict__ b2,
    ushort* __restrict__ Wp1, ushort* __restrict__ Wp2)
{
    int idx = blockIdx.x * blockDim.x + threadIdx.x;
    const int n1 = NR * DD * DD;
    const int n2 = NR * DD * OD;
    if (idx < n1) {
        int r = idx >> 12, rem = idx & 4095;
        int i = rem >> 6, o = rem & 63;
        float s = 0.f;
        #pragma unroll
        for (int b = 0; b < NBASE; ++b) s += wc1[r * NBASE + b] * b1[b * 4096 + rem];
        Wp1[(((size_t)(r * 8 + (i >> 3)) * 64 + o) << 3) + (i & 7)] = f2bf(s);
    } else if (idx < n1 + n2) {
        int j = idx - n1;
        int r = j >> 10, rem = j & 1023;
        int i = rem >> 4, o = rem & 15;
        float s = 0.f;
        #pragma unroll
        for (int b = 0; b < NBASE; ++b) s += wc2[r * NBASE + b] * b2[b * 1024 + rem];
        Wp2[(((size_t)(r * 8 + (i >> 3)) * 16 + o) << 3) + (i & 7)] = f2bf(s);
    }
}

// ---------------- CSR build: pass A — per-(block,bucket) counts ----------------
__global__ __launch_bounds__(256) void count_kernel(Edges ep, int* __restrict__ cnt_mat)
{
    __shared__ int h[NBK];
    int r = blockIdx.y, blk = blockIdx.x;
    const int* __restrict__ dst = ep.dst[r];
    const int chunk = (EE + SBLK - 1) / SBLK;
    int e0 = blk * chunk, e1 = min(e0 + chunk, EE);
    for (int i = threadIdx.x; i < NBK; i += 256) h[i] = 0;
    __syncthreads();
    for (int e = e0 + threadIdx.x; e < e1; e += 256)
        atomicAdd(&h[dst[e] >> BSH], 1);
    __syncthreads();
    for (int b = threadIdx.x; b < NBK; b += 256)
        cnt_mat[r * FLATN + b * SBLK + blk] = h[b];
}

// ---------------- pass B — flat exclusive scan over (bucket, block) per rel ----------------
__global__ __launch_bounds__(1024) void flat_scan_kernel(
    const int* __restrict__ cnt_mat, int* __restrict__ off_flat, int* __restrict__ bbase)
{
    __shared__ int wsum[16];
    const int TPE = 13;
    int r = blockIdx.x;
    int tid = threadIdx.x, lane = tid & 63, wid = tid >> 6;
    int base = tid * TPE;
    int v[TPE];
    int s = 0;
    #pragma unroll
    for (int j = 0; j < TPE; ++j) {
        int i = base + j;
        v[j] = (i < FLATN) ? cnt_mat[r * FLATN + i] : 0;
        s += v[j];
    }
    int si = s;
    #pragma unroll
    for (int off = 1; off < 64; off <<= 1) {
        int t = __shfl_up(si, off);
        if (lane >= off) si += t;
    }
    if (lane == 63) wsum[wid] = si;
    __syncthreads();
    if (wid == 0) {
        int ws = (lane < 16) ? wsum[lane] : 0;
        #pragma unroll
        for (int off = 1; off < 16; off <<= 1) {
            int t = __shfl_up(ws, off);
            if (lane >= off) ws += t;
        }
        if (lane < 16) wsum[lane] = ws;
    }
    __syncthreads();
    int texcl = (wid > 0 ? wsum[wid - 1] : 0) + (si - s);
    int part = 0;
    #pragma unroll
    for (int j = 0; j < TPE; ++j) {
        int i = base + j;
        if (i < FLATN) {
            int o = texcl + part;
            off_flat[r * FLATN + i] = o;
            if ((i & (SBLK - 1)) == 0) bbase[r * (NBK + 1) + (i >> 7)] = o;
        }
        part += v[j];
    }
    if (tid == 0) bbase[r * (NBK + 1) + NBK] = EE;
}

// ---------------- pass C — scatter with precomputed cursors ----------------
__global__ __launch_bounds__(256) void scatter2_kernel(
    Edges ep, const int* __restrict__ off_flat, unsigned int* __restrict__ ebuf)
{
    __shared__ int goff[NBK];
    __shared__ int lcnt[NBK];
    int r = blockIdx.y, blk = blockIdx.x;
    const int* __restrict__ src = ep.src[r];
    const int* __restrict__ dst = ep.dst[r];
    unsigned int* eb = ebuf + (size_t)r * EE;
    const int chunk = (EE + SBLK - 1) / SBLK;
    int e0 = blk * chunk, e1 = min(e0 + chunk, EE);
    if (threadIdx.x < NBK) {
        goff[threadIdx.x] = off_flat[r * FLATN + threadIdx.x * SBLK + blk];
        lcnt[threadIdx.x] = 0;
    }
    __syncthreads();
    for (int e = e0 + threadIdx.x; e < e1; e += 256) {
        int d = dst[e];
        int b = d >> BSH;
        int pos = goff[b] + atomicAdd(&lcnt[b], 1);
        eb[pos] = (unsigned int)src[e] | ((unsigned int)(d & 1023) << 17);
    }
}

// ---------------- pass D — per-(bucket,rel) fine CSR ----------------
__global__ __launch_bounds__(256) void csr_fine_kernel(
    const unsigned int* __restrict__ ebuf, const int* __restrict__ bbase,
    int* __restrict__ row_ptr, float* __restrict__ inv_deg, int* __restrict__ col_idx)
{
    __shared__ int nh[1024];
    __shared__ int nb[1024];
    __shared__ int wsum4[4];
    __shared__ int stage[STCAP];
    int r = blockIdx.y, b = blockIdx.x;
    int tid = threadIdx.x, lane = tid & 63, wid = tid >> 6;
    int gb = bbase[r * (NBK + 1) + b];
    int ge = bbase[r * (NBK + 1) + b + 1];
    int cnt = ge - gb;
    if (cnt > STCAP) cnt = STCAP;
    const unsigned int* eb = ebuf + (size_t)r * EE + gb;
    #pragma unroll
    for (int j = 0; j < 4; ++j) nh[tid * 4 + j] = 0;
    __syncthreads();
    for (int i = tid; i < cnt; i += 256)
        atomicAdd(&nh[(eb[i] >> 17) & 1023], 1);
    __syncthreads();
    int v0 = nh[tid * 4 + 0], v1 = nh[tid * 4 + 1], v2 = nh[tid * 4 + 2], v3 = nh[tid * 4 + 3];
    int s = v0 + v1 + v2 + v3;
    int si = s;
    #pragma unroll
    for (int off = 1; off < 64; off <<= 1) {
        int t = __shfl_up(si, off);
        if (lane >= off) si += t;
    }
    if (lane == 63) wsum4[wid] = si;
    __syncthreads();
    if (tid == 0) {
        int a = 0;
        #pragma unroll
        for (int k = 0; k < 4; ++k) { int t = wsum4[k]; wsum4[k] = a; a += t; }
    }
    __syncthreads();
    int texcl = wsum4[wid] + (si - s);
    int p0 = texcl, p1 = p0 + v0, p2 = p1 + v1, p3 = p2 + v2;
    nb[tid * 4 + 0] = p0; nb[tid * 4 + 1] = p1; nb[tid * 4 + 2] = p2; nb[tid * 4 + 3] = p3;
    {
        int node0 = b * 1024 + tid * 4;
        int pj[4] = { p0, p1, p2, p3 };
        int vj[4] = { v0, v1, v2, v3 };
        #pragma unroll
        for (int j = 0; j < 4; ++j) {
            int node = node0 + j;
            if (node < NN) {
                row_ptr[r * (NN + 1) + node] = gb + pj[j];
                inv_deg[r * NN + node] = 1.0f / (float)(vj[j] > 1 ? vj[j] : 1);
            }
        }
    }
    if (b == NBK - 1 && tid == 0) row_ptr[r * (NN + 1) + NN] = EE;
    #pragma unroll
    for (int j = 0; j < 4; ++j) nh[tid * 4 + j] = 0;
    __syncthreads();
    for (int i = tid; i < cnt; i += 256) {
        unsigned int w = eb[i];
        int loc = (w >> 17) & 1023;
        int pos = nb[loc] + atomicAdd(&nh[loc], 1);
        stage[pos] = (int)(w & 0x1ffffu);
    }
    __syncthreads();
    int* co = col_idx + (size_t)r * EE + gb;
    for (int i = tid; i < cnt; i += 256) co[i] = stage[i];
}

// ---------------- bucket-local sum-degree sort: vr 0 = dstA {1,2,5}, vr 1 = dstB {0,3,4} ----------------
__device__ __forceinline__ int sdeg(int vr, int n, const int* __restrict__ rp)
{
    if (vr == 0)
        return (rp[1 * (NN + 1) + n + 1] - rp[1 * (NN + 1) + n])
             + (rp[2 * (NN + 1) + n + 1] - rp[2 * (NN + 1) + n])
             + (rp[5 * (NN + 1) + n + 1] - rp[5 * (NN + 1) + n]);
    return (rp[0 * (NN + 1) + n + 1] - rp[0 * (NN + 1) + n])
         + (rp[3 * (NN + 1) + n + 1] - rp[3 * (NN + 1) + n])
         + (rp[4 * (NN + 1) + n + 1] - rp[4 * (NN + 1) + n]);
}

__global__ __launch_bounds__(256) void bsort_kernel(
    const int* __restrict__ row_ptr, int* __restrict__ perm, int* __restrict__ iperm)
{
    __shared__ int h[DBIN];
    __shared__ int base_[DBIN];
    int vr = blockIdx.y, b = blockIdx.x;
    int n0 = b * 1024;
    int cnt = min(1024, NN - n0);
    int tid = threadIdx.x;
    if (tid < DBIN) h[tid] = 0;
    __syncthreads();
    int bin[4];
    #pragma unroll
    for (int j = 0; j < 4; ++j) {
        int i = tid + j * 256;
        if (i < cnt) {
            bin[j] = min(sdeg(vr, n0 + i, row_ptr), DBIN - 1);
            atomicAdd(&h[bin[j]], 1);
        } else bin[j] = -1;
    }
    __syncthreads();
    if (tid < 64) {
        int v = h[tid];
        int s = v;
        #pragma unroll
        for (int off = 1; off < 64; off <<= 1) {
            int t = __shfl_up(s, off);
            if (tid >= off) s += t;
        }
        base_[tid] = s - v;
        h[tid] = 0;
    }
    __syncthreads();
    #pragma unroll
    for (int j = 0; j < 4; ++j) {
        if (bin[j] >= 0) {
            int n = n0 + tid + j * 256;
            int pos = n0 + base_[bin[j]] + atomicAdd(&h[bin[j]], 1);
            perm[vr * NN + pos] = n;
            iperm[vr * NN + n] = pos;
        }
    }
}

// ---------------- translate col_idx in place through iperm of the src side ----------------
__global__ __launch_bounds__(256) void translate_kernel(
    const int* __restrict__ iperm, int* __restrict__ col_idx)
{
    const int srcSide[NR] = {0, 1, 0, 1, 0, 1};   // A=0, B=1
    int r = blockIdx.y;
    const int* ip = iperm + srcSide[r] * NN;
    int* ci = col_idx + (size_t)r * EE;
    for (int e = blockIdx.x * 256 + threadIdx.x; e < EE; e += gridDim.x * 256)
        ci[e] = ip[ci[e]];
}

// ---------------- embeddings -> bf16, stored in permuted (processing) order ----------------
__global__ __launch_bounds__(256) void cvtp_kernel(
    const float* __restrict__ inA, const float* __restrict__ inB,
    const int* __restrict__ perm, ushort* __restrict__ outA, ushort* __restrict__ outB)
{
    int side = blockIdx.y;
    int t = blockIdx.x * 256 + threadIdx.x;
    if (t >= NN * 8) return;
    int idx = t >> 3, j = t & 7;
    int n = perm[side * NN + idx];
    const float* in = side ? inB : inA;
    ushort* out = side ? outB : outA;
    float4 v0 = ((const float4*)in)[n * 16 + j * 2];
    float4 v1 = ((const float4*)in)[n * 16 + j * 2 + 1];
    int4 o;
    o.x = (int)((unsigned int)f2bf(v0.x) | ((unsigned int)f2bf(v0.y) << 16));
    o.y = (int)((unsigned int)f2bf(v0.z) | ((unsigned int)f2bf(v0.w) << 16));
    o.z = (int)((unsigned int)f2bf(v1.x) | ((unsigned int)f2bf(v1.y) << 16));
    o.w = (int)((unsigned int)f2bf(v1.z) | ((unsigned int)f2bf(v1.w) << 16));
    *(int4*)(out + (size_t)idx * DD + j * 8) = o;
}

// ---------------- fused layer-0 (grid-stride): gather 3 rels + bias + relu -> h0p ----------------
__global__ __launch_bounds__(256) void layer0_kernel(
    const ushort* __restrict__ eA, const ushort* __restrict__ eB,
    const int* __restrict__ row_ptr, const int* __restrict__ col_idx,
    const float* __restrict__ inv_deg, const int* __restrict__ perm,
    const float* __restrict__ bias, ushort* __restrict__ hA, ushort* __restrict__ hB)
{
    int side = blockIdx.y;
    const int relT[2][3] = { {1, 2, 5}, {0, 3, 4} };
    int r0 = relT[side][0], r1 = relT[side][1], r2 = relT[side][2];
    const ushort* F0 = (side == 0) ? eB : eA;
    const ushort* F1 = (side == 0) ? eA : eB;
    const ushort* F2 = F0;
    const int* rp0 = row_ptr + r0 * (NN + 1);
    const int* rp1 = row_ptr + r1 * (NN + 1);
    const int* rp2 = row_ptr + r2 * (NN + 1);
    const int* ci0 = col_idx + (size_t)r0 * EE;
    const int* ci1 = col_idx + (size_t)r1 * EE;
    const int* ci2 = col_idx + (size_t)r2 * EE;
    ushort* hout = side ? hB : hA;
    const int* pm = perm + side * NN;
    int tid = threadIdx.x;
    int wid = tid >> 6, lane = tid & 63;
    int grp = lane >> 3, sub = lane & 7;
    float bvec[8];
    {
        float4 b0 = *(const float4*)(bias + sub * 8);
        float4 b1 = *(const float4*)(bias + sub * 8 + 4);
        bvec[0] = b0.x; bvec[1] = b0.y; bvec[2] = b0.z; bvec[3] = b0.w;
        bvec[4] = b1.x; bvec[5] = b1.y; bvec[6] = b1.z; bvec[7] = b1.w;
    }
    for (int idx = blockIdx.x * 32 + wid * 8 + grp; idx < NN; idx += gridDim.x * 32) {
        int n = pm[idx];
        // hoist all row_ptr loads (independent)
        int s0 = rp0[n], e0 = rp0[n + 1];
        int s1 = rp1[n], e1 = rp1[n + 1];
        int s2 = rp2[n], e2 = rp2[n + 1];
        float i0 = inv_deg[r0 * NN + n];
        float i1 = inv_deg[r1 * NN + n];
        float i2 = inv_deg[r2 * NN + n];
        float a0[8] = {}, a1[8] = {}, a2[8] = {};
        gather8(F0, ci0, s0, e0, sub, a0);
        gather8(F1, ci1, s1, e1, sub, a1);
        gather8(F2, ci2, s2, e2, sub, a2);
        float acc[8];
        #pragma unroll
        for (int j = 0; j < 8; ++j)
            acc[j] = fmaxf(a0[j] * i0 + a1[j] * i1 + a2[j] * i2 + bvec[j], 0.f);
        int4 o;
        o.x = (int)((unsigned int)f2bf(acc[0]) | ((unsigned int)f2bf(acc[1]) << 16));
        o.y = (int)((unsigned int)f2bf(acc[2]) | ((unsigned int)f2bf(acc[3]) << 16));
        o.z = (int)((unsigned int)f2bf(acc[4]) | ((unsigned int)f2bf(acc[5]) << 16));
        o.w = (int)((unsigned int)f2bf(acc[6]) | ((unsigned int)f2bf(acc[7]) << 16));
        *(int4*)(hout + (size_t)idx * DD + sub * 8) = o;
    }
}

// ---------------- fused layer-1 (grid-stride): gather -> LDS -> MFMA -> h1p ----------------
__global__ __launch_bounds__(256) void layer1_fused_kernel(
    const ushort* __restrict__ h0A, const ushort* __restrict__ h0B,
    const int* __restrict__ row_ptr, const int* __restrict__ col_idx,
    const float* __restrict__ inv_deg, const int* __restrict__ perm,
    const ushort* __restrict__ Wp, const float* __restrict__ bias,
    ushort* __restrict__ h1A, ushort* __restrict__ h1B)
{
    __shared__ unsigned int sZ[32 * LROW];   // 12.8 KB; reused as bf16 C-stage
    int side = blockIdx.y;
    const int relT[2][3] = { {1, 2, 5}, {0, 3, 4} };
    int rr0 = relT[side][0], rr1 = relT[side][1], rr2 = relT[side][2];
    const ushort* F0 = (side == 0) ? h0B : h0A;
    const ushort* F1 = (side == 0) ? h0A : h0B;
    const ushort* F2 = F0;
    const int* rp0 = row_ptr + rr0 * (NN + 1);
    const int* rp1 = row_ptr + rr1 * (NN + 1);
    const int* rp2 = row_ptr + rr2 * (NN + 1);
    const int* ci0 = col_idx + (size_t)rr0 * EE;
    const int* ci1 = col_idx + (size_t)rr1 * EE;
    const int* ci2 = col_idx + (size_t)rr2 * EE;
    ushort* out = side ? h1B : h1A;
    const int* pm = perm + side * NN;
    int tid = threadIdx.x;
    int wid = tid >> 6, lane = tid & 63;
    int grp = lane >> 3, sub = lane & 7;
    int ln = wid * 8 + grp;
    int q = lane & 15, p = lane >> 4;
    int base16 = (wid >> 1) * 16, cb = (wid & 1) * 32;
    float bv0 = bias[cb + q], bv1 = bias[cb + 16 + q];
    for (int idx0 = blockIdx.x * 32; idx0 < NN; idx0 += gridDim.x * 32) {
        int idx = idx0 + ln;
        bool valid = (idx < NN);
        int n = valid ? pm[idx] : 0;
        int s0 = valid ? rp0[n] : 0, e0 = valid ? rp0[n + 1] : 0;
        int s1 = valid ? rp1[n] : 0, e1 = valid ? rp1[n + 1] : 0;
        int s2 = valid ? rp2[n] : 0, e2 = valid ? rp2[n + 1] : 0;
        float i0 = valid ? inv_deg[rr0 * NN + n] : 0.f;
        float i1 = valid ? inv_deg[rr1 * NN + n] : 0.f;
        float i2 = valid ? inv_deg[rr2 * NN + n] : 0.f;
        float a0[8] = {}, a1[8] = {}, a2[8] = {};
        gather8(F0, ci0, s0, e0, sub, a0);
        gather8(F1, ci1, s1, e1, sub, a1);
        gather8(F2, ci2, s2, e2, sub, a2);
        int4 o0, o1, o2;
        o0.x = (int)((unsigned int)f2bf(a0[0] * i0) | ((unsigned int)f2bf(a0[1] * i0) << 16));
        o0.y = (int)((unsigned int)f2bf(a0[2] * i0) | ((unsigned int)f2bf(a0[3] * i0) << 16));
        o0.z = (int)((unsigned int)f2bf(a0[4] * i0) | ((unsigned int)f2bf(a0[5] * i0) << 16));
        o0.w = (int)((unsigned int)f2bf(a0[6] * i0) | ((unsigned int)f2bf(a0[7] * i0) << 16));
        o1.x = (int)((unsigned int)f2bf(a1[0] * i1) | ((unsigned int)f2bf(a1[1] * i1) << 16));
        o1.y = (int)((unsigned int)f2bf(a1[2] * i1) | ((unsigned int)f2bf(a1[3] * i1) << 16));
        o1.z = (int)((unsigned int)f2bf(a1[4] * i1) | ((unsigned int)f2bf(a1[5] * i1) << 16));
        o1.w = (int)((unsigned int)f2bf(a1[6] * i1) | ((unsigned int)f2bf(a1[7] * i1) << 16));
        o2.x = (int)((unsigned int)f2bf(a2[0] * i2) | ((unsigned int)f2bf(a2[1] * i2) << 16));
        o2.y = (int)((unsigned int)f2bf(a2[2] * i2) | ((unsigned int)f2bf(a2[3] * i2) << 16));
        o2.z = (int)((unsigned int)f2bf(a2[4] * i2) | ((unsigned int)f2bf(a2[5] * i2) << 16));
        o2.w = (int)((unsigned int)f2bf(a2[6] * i2) | ((unsigned int)f2bf(a2[7] * i2) << 16));
        *(int4*)&sZ[ln * LROW + 0 * 32 + sub * 4] = o0;
        *(int4*)&sZ[ln * LROW + 1 * 32 + sub * 4] = o1;
        *(int4*)&sZ[ln * LROW + 2 * 32 + sub * 4] = o2;
        __syncthreads();
        f32x4 acc0 = {0.f, 0.f, 0.f, 0.f};
        f32x4 acc1 = {0.f, 0.f, 0.f, 0.f};
        const int rels[3] = { rr0, rr1, rr2 };
        #pragma unroll
        for (int ks = 0; ks < 3; ++ks) {
            int rel = rels[ks];
            #pragma unroll
            for (int tt = 0; tt < 2; ++tt) {
                int4 t4 = *(const int4*)&sZ[(base16 + q) * LROW + (ks * 2 + tt) * 16 + p * 4];
                bf16x8 a = *(const bf16x8*)&t4;
                const ushort* wb = Wp + (((size_t)(rel * 8 + tt * 4 + p) * 64 + cb + q) << 3);
                bf16x8 b0 = *(const bf16x8*)wb;
                bf16x8 b1 = *(const bf16x8*)(wb + 16 * 8);
                acc0 = __builtin_amdgcn_mfma_f32_16x16x32_bf16(a, b0, acc0, 0, 0, 0);
                acc1 = __builtin_amdgcn_mfma_f32_16x16x32_bf16(a, b1, acc1, 0, 0, 0);
            }
        }
        __syncthreads();
        ushort* sC = (ushort*)sZ;
        #pragma unroll
        for (int v = 0; v < 4; ++v) {
            int row = base16 + p * 4 + v;
            sC[row * 64 + cb + q]      = f2bf(fmaxf(acc0[v] + bv0, 0.f));
            sC[row * 64 + cb + 16 + q] = f2bf(fmaxf(acc1[v] + bv1, 0.f));
        }
        __syncthreads();
        int row = tid >> 3, c8 = (tid & 7) * 8;
        if (idx0 + row < NN)
            *(int4*)(out + (size_t)(idx0 + row) * DD + c8) = *(const int4*)(sC + row * 64 + c8);
        __syncthreads();
    }
}

// ---------------- fused layer-2 (grid-stride): gather -> LDS -> MFMA (16 out) -> d_out ----------------
__global__ __launch_bounds__(256) void layer2_fused_kernel(
    const ushort* __restrict__ h1A, const ushort* __restrict__ h1B,
    const int* __restrict__ row_ptr, const int* __restrict__ col_idx,
    const float* __restrict__ inv_deg, const int* __restrict__ perm,
    const ushort* __restrict__ Wp, const float* __restrict__ bias,
    float* __restrict__ out)
{
    __shared__ unsigned int sZ[32 * LROW];
    const int rr0 = 1, rr1 = 2, rr2 = 5;
    const int* rp0 = row_ptr + rr0 * (NN + 1);
    const int* rp1 = row_ptr + rr1 * (NN + 1);
    const int* rp2 = row_ptr + rr2 * (NN + 1);
    const int* ci0 = col_idx + (size_t)rr0 * EE;
    const int* ci1 = col_idx + (size_t)rr1 * EE;
    const int* ci2 = col_idx + (size_t)rr2 * EE;
    int tid = threadIdx.x;
    int wid = tid >> 6, lane = tid & 63;
    int grp = lane >> 3, sub = lane & 7;
    int ln = wid * 8 + grp;
    int q = lane & 15, p = lane >> 4;
    for (int idx0 = blockIdx.x * 32; idx0 < NN; idx0 += gridDim.x * 32) {
        int idx = idx0 + ln;
        bool valid = (idx < NN);
        int n = valid ? perm[idx] : 0;
        int s0 = valid ? rp0[n] : 0, e0 = valid ? rp0[n + 1] : 0;
        int s1 = valid ? rp1[n] : 0, e1 = valid ? rp1[n + 1] : 0;
        int s2 = valid ? rp2[n] : 0, e2 = valid ? rp2[n + 1] : 0;
        float i0 = valid ? inv_deg[rr0 * NN + n] : 0.f;
        float i1 = valid ? inv_deg[rr1 * NN + n] : 0.f;
        float i2 = valid ? inv_deg[rr2 * NN + n] : 0.f;
        float a0[8] = {}, a1[8] = {}, a2[8] = {};
        gather8(h1B, ci0, s0, e0, sub, a0);
        gather8(h1A, ci1, s1, e1, sub, a1);
        gather8(h1B, ci2, s2, e2, sub, a2);
        int4 o0, o1, o2;
        o0.x = (int)((unsigned int)f2bf(a0[0] * i0) | ((unsigned int)f2bf(a0[1] * i0) << 16));
        o0.y = (int)((unsigned int)f2bf(a0[2] * i0) | ((unsigned int)f2bf(a0[3] * i0) << 16));
        o0.z = (int)((unsigned int)f2bf(a0[4] * i0) | ((unsigned int)f2bf(a0[5] * i0) << 16));
        o0.w = (int)((unsigned int)f2bf(a0[6] * i0) | ((unsigned int)f2bf(a0[7] * i0) << 16));
        o1.x = (int)((unsigned int)f2bf(a1[0] * i1) | ((unsigned int)f2bf(a1[1] * i1) << 16));
        o1.y = (int)((unsigned int)f2bf(a1[2] * i1) | ((unsigned int)f2bf(a1[3] * i1) << 16));
        o1.z = (int)((unsigned int)f2bf(a1[4] * i1) | ((unsigned int)f2bf(a1[5] * i1) << 16));
        o1.w = (int)((unsigned int)f2bf(a1[6] * i1) | ((unsigned int)f2bf(a1[7] * i1) << 16));
        o2.x = (int)((unsigned int)f2bf(a2[0] * i2) | ((unsigned int)f2bf(a2[1] * i2) << 16));
        o2.y = (int)((unsigned int)f2bf(a2[2] * i2) | ((unsigned int)f2bf(a2[3] * i2) << 16));
        o2.z = (int)((unsigned int)f2bf(a2[4] * i2) | ((unsigned int)f2bf(a2[5] * i2) << 16));
        o2.w = (int)((unsigned int)f2bf(a2[6] * i2) | ((unsigned int)f2bf(a2[7] * i2) << 16));
        *(int4*)&sZ[ln * LROW + 0 * 32 + sub * 4] = o0;
        *(int4*)&sZ[ln * LROW + 1 * 32 + sub * 4] = o1;
        *(int4*)&sZ[ln * LROW + 2 * 32 + sub * 4] = o2;
        __syncthreads();
        if (wid < 2) {
            int base16 = wid * 16;
            f32x4 acc = {0.f, 0.f, 0.f, 0.f};
            const int rels[3] = { rr0, rr1, rr2 };
            #pragma unroll
            for (int ks = 0; ks < 3; ++ks) {
                int rel = rels[ks];
                #pragma unroll
                for (int tt = 0; tt < 2; ++tt) {
                    int4 t4 = *(const int4*)&sZ[(base16 + q) * LROW + (ks * 2 + tt) * 16 + p * 4];
                    bf16x8 a = *(const bf16x8*)&t4;
                    bf16x8 b = *(const bf16x8*)(Wp + (((size_t)(rel * 8 + tt * 4 + p) * 16 + q) << 3));
                    acc = __builtin_amdgcn_mfma_f32_16x16x32_bf16(a, b, acc, 0, 0, 0);
                }
            }
            float bv = bias[q];
            #pragma unroll
            for (int v = 0; v < 4; ++v) {
                int ridx = idx0 + base16 + p * 4 + v;
                if (ridx < NN) {
                    int pn = perm[ridx];
                    out[(size_t)pn * OD + q] = acc[v] + bv;
                }
            }
        }
        __syncthreads();
    }
}

extern "C" void kernel_launch(void* const* d_in, const int* in_sizes, int n_in,
                              void* d_out, int out_size, void* d_ws, size_t ws_size,
                              hipStream_t stream)
{
    const float* embA  = (const float*)d_in[0];
    const float* embB  = (const float*)d_in[1];
    const float* bias0 = (const float*)d_in[2];
    const float* wc1   = (const float*)d_in[3];
    const float* b1    = (const float*)d_in[4];
    const float* bias1 = (const float*)d_in[5];
    const float* wc2   = (const float*)d_in[6];
    const float* b2    = (const float*)d_in[7];
    const float* bias2 = (const float*)d_in[8];

    Edges ep;
    for (int r = 0; r < NR; ++r) {
        ep.src[r] = (const int*)d_in[9 + 2 * r];
        ep.dst[r] = (const int*)d_in[10 + 2 * r];
    }

    char* ws = (char*)d_ws;
    size_t off = 0;
    auto alloc = [&](size_t bytes) {
        void* p = ws + off;
        off = (off + bytes + 255) & ~(size_t)255;
        return p;
    };
    ushort* Wp1     = (ushort*)alloc((size_t)NR * 8 * 64 * 8 * 2);
    ushort* Wp2     = (ushort*)alloc((size_t)NR * 8 * 16 * 8 * 2);
    int*    cnt_mat = (int*)   alloc((size_t)NR * FLATN * 4);
    int*    off_fl  = (int*)   alloc((size_t)NR * FLATN * 4);
    int*    bbase   = (int*)   alloc((size_t)NR * (NBK + 1) * 4);
    int*    row_ptr = (int*)   alloc((size_t)NR * (NN + 1) * 4);
    float*  inv_deg = (float*) alloc((size_t)NR * NN * 4);
    int*    col_idx = (int*)   alloc((size_t)NR * EE * 4);
    int*    perm    = (int*)   alloc((size_t)2 * NN * 4);
    int*    iperm   = (int*)   alloc((size_t)2 * NN * 4);
    ushort* reg1    = (ushort*)alloc((size_t)2 * NN * DD * 2);   // ebuf -> embp -> h1p
    ushort* h0pA    = (ushort*)alloc((size_t)NN * DD * 2);
    ushort* h0pB    = (ushort*)alloc((size_t)NN * DD * 2);
    (void)ws_size;

    // lifetime-disjoint aliases inside reg1 (25.6 MB):
    unsigned int* ebuf  = (unsigned int*)reg1;       // dead after csr_fine
    ushort*       embpA = reg1;                      // written by cvtp (after csr_fine), dead after layer0
    ushort*       embpB = reg1 + (size_t)NN * DD;
    ushort*       h1pA  = reg1;                      // written by layer1 (after layer0)
    ushort*       h1pB  = reg1 + (size_t)NN * DD;

    int nw = NR * DD * DD + NR * DD * OD;
    build_w_kernel<<<(nw + 255) / 256, 256, 0, stream>>>(wc1, b1, wc2, b2, Wp1, Wp2);

    count_kernel<<<dim3(SBLK, NR), 256, 0, stream>>>(ep, cnt_mat);
    flat_scan_kernel<<<NR, 1024, 0, stream>>>(cnt_mat, off_fl, bbase);
    scatter2_kernel<<<dim3(SBLK, NR), 256, 0, stream>>>(ep, off_fl, ebuf);
    csr_fine_kernel<<<dim3(NBK, NR), 256, 0, stream>>>(ebuf, bbase, row_ptr, inv_deg, col_idx);

    bsort_kernel<<<dim3(NBK, 2), 256, 0, stream>>>(row_ptr, perm, iperm);
    translate_kernel<<<dim3(64, NR), 256, 0, stream>>>(iperm, col_idx);
    cvtp_kernel<<<dim3((NN * 8 + 255) / 256, 2), 256, 0, stream>>>(
        embA, embB, perm, embpA, embpB);

    // relations: r0 A->B, r1 B->A, r2 A->A, r3 B->B, r4 A->B, r5 B->A
    // dst A: rels {1,2,5} srcs {B,A,B};  dst B: rels {0,3,4} srcs {A,B,A}

    // grid-stride resident grids: ~2048 blocks total (8 blocks/CU x 256 CU)
    layer0_kernel<<<dim3(1024, 2), 256, 0, stream>>>(
        embpA, embpB, row_ptr, col_idx, inv_deg, perm, bias0, h0pA, h0pB);

    layer1_fused_kernel<<<dim3(1024, 2), 256, 0, stream>>>(
        h0pA, h0pB, row_ptr, col_idx, inv_deg, perm, Wp1, bias1, h1pA, h1pB);

    layer2_fused_kernel<<<2048, 256, 0, stream>>>(
        h1pA, h1pB, row_ptr, col_idx, inv_deg, perm, Wp2, bias2, (float*)d_out);
}

// Round 13
// 300.718 us; speedup vs baseline: 1.1966x; 1.1966x over previous
//
#include <hip/hip_runtime.h>

#define NN 100000
#define EE 500000
#define DD 64
#define OD 16
#define NR 6
#define NBASE 4
#define BSH 10
#define NBK 98         /* ceil(NN / 1024) */
#define SBLK 128       /* scatter blocks per relation */
#define FLATN (NBK * SBLK)   /* 12544 */
#define STCAP 5632     /* fine-bucket edge capacity */
#define DBIN 64        /* degree-sort bins */
#define LROW 100       /* LDS row stride in dwords (padded, 16B-aligned) */

struct Edges { const int* src[NR]; const int* dst[NR]; };

typedef __attribute__((ext_vector_type(8))) short bf16x8;
typedef __attribute__((ext_vector_type(4))) float f32x4;

__device__ __forceinline__ float bf2f(ushort u) {
    union { unsigned int i; float f; } v; v.i = ((unsigned int)u) << 16; return v.f;
}
__device__ __forceinline__ ushort f2bf(float f) {
    unsigned int x = __float_as_uint(f);
    unsigned int r = (x + 0x7fffu + ((x >> 16) & 1u)) >> 16;
    return (ushort)r;
}
__device__ __forceinline__ void bfpair(unsigned int u, float& lo, float& hi) {
    lo = __uint_as_float(u << 16);
    hi = __uint_as_float(u & 0xffff0000u);
}

// ---------------- W = einsum('rb,bio->rio'), emitted bf16 B-fragment-packed ----------------
__global__ __launch_bounds__(256) void build_w_kernel(
    const float* __restrict__ wc1, const float* __restrict__ b1,
    const float* __restrict__ wc2, const float* __restrict__ b2,
    ushort* __restrict__ Wp1, ushort* __restrict__ Wp2)
{
    int idx = blockIdx.x * blockDim.x + threadIdx.x;
    const int n1 = NR * DD * DD;
    const int n2 = NR * DD * OD;
    if (idx < n1) {
        int r = idx >> 12, rem = idx & 4095;
        int i = rem >> 6, o = rem & 63;
        float s = 0.f;
        #pragma unroll
        for (int b = 0; b < NBASE; ++b) s += wc1[r * NBASE + b] * b1[b * 4096 + rem];
        Wp1[(((size_t)(r * 8 + (i >> 3)) * 64 + o) << 3) + (i & 7)] = f2bf(s);
    } else if (idx < n1 + n2) {
        int j = idx - n1;
        int r = j >> 10, rem = j & 1023;
        int i = rem >> 4, o = rem & 15;
        float s = 0.f;
        #pragma unroll
        for (int b = 0; b < NBASE; ++b) s += wc2[r * NBASE + b] * b2[b * 1024 + rem];
        Wp2[(((size_t)(r * 8 + (i >> 3)) * 16 + o) << 3) + (i & 7)] = f2bf(s);
    }
}

// ---------------- CSR build: pass A — per-(block,bucket) counts ----------------
__global__ __launch_bounds__(256) void count_kernel(Edges ep, int* __restrict__ cnt_mat)
{
    __shared__ int h[NBK];
    int r = blockIdx.y, blk = blockIdx.x;
    const int* __restrict__ dst = ep.dst[r];
    const int chunk = (EE + SBLK - 1) / SBLK;
    int e0 = blk * chunk, e1 = min(e0 + chunk, EE);
    for (int i = threadIdx.x; i < NBK; i += 256) h[i] = 0;
    __syncthreads();
    for (int e = e0 + threadIdx.x; e < e1; e += 256)
        atomicAdd(&h[dst[e] >> BSH], 1);
    __syncthreads();
    for (int b = threadIdx.x; b < NBK; b += 256)
        cnt_mat[r * FLATN + b * SBLK + blk] = h[b];
}

// ---------------- pass B — flat exclusive scan over (bucket, block) per rel ----------------
__global__ __launch_bounds__(1024) void flat_scan_kernel(
    const int* __restrict__ cnt_mat, int* __restrict__ off_flat, int* __restrict__ bbase)
{
    __shared__ int wsum[16];
    const int TPE = 13;
    int r = blockIdx.x;
    int tid = threadIdx.x, lane = tid & 63, wid = tid >> 6;
    int base = tid * TPE;
    int v[TPE];
    int s = 0;
    #pragma unroll
    for (int j = 0; j < TPE; ++j) {
        int i = base + j;
        v[j] = (i < FLATN) ? cnt_mat[r * FLATN + i] : 0;
        s += v[j];
    }
    int si = s;
    #pragma unroll
    for (int off = 1; off < 64; off <<= 1) {
        int t = __shfl_up(si, off);
        if (lane >= off) si += t;
    }
    if (lane == 63) wsum[wid] = si;
    __syncthreads();
    if (wid == 0) {
        int ws = (lane < 16) ? wsum[lane] : 0;
        #pragma unroll
        for (int off = 1; off < 16; off <<= 1) {
            int t = __shfl_up(ws, off);
            if (lane >= off) ws += t;
        }
        if (lane < 16) wsum[lane] = ws;
    }
    __syncthreads();
    int texcl = (wid > 0 ? wsum[wid - 1] : 0) + (si - s);
    int part = 0;
    #pragma unroll
    for (int j = 0; j < TPE; ++j) {
        int i = base + j;
        if (i < FLATN) {
            int o = texcl + part;
            off_flat[r * FLATN + i] = o;
            if ((i & (SBLK - 1)) == 0) bbase[r * (NBK + 1) + (i >> 7)] = o;
        }
        part += v[j];
    }
    if (tid == 0) bbase[r * (NBK + 1) + NBK] = EE;
}

// ---------------- pass C — scatter with precomputed cursors ----------------
__global__ __launch_bounds__(256) void scatter2_kernel(
    Edges ep, const int* __restrict__ off_flat, unsigned int* __restrict__ ebuf)
{
    __shared__ int goff[NBK];
    __shared__ int lcnt[NBK];
    int r = blockIdx.y, blk = blockIdx.x;
    const int* __restrict__ src = ep.src[r];
    const int* __restrict__ dst = ep.dst[r];
    unsigned int* eb = ebuf + (size_t)r * EE;
    const int chunk = (EE + SBLK - 1) / SBLK;
    int e0 = blk * chunk, e1 = min(e0 + chunk, EE);
    if (threadIdx.x < NBK) {
        goff[threadIdx.x] = off_flat[r * FLATN + threadIdx.x * SBLK + blk];
        lcnt[threadIdx.x] = 0;
    }
    __syncthreads();
    for (int e = e0 + threadIdx.x; e < e1; e += 256) {
        int d = dst[e];
        int b = d >> BSH;
        int pos = goff[b] + atomicAdd(&lcnt[b], 1);
        eb[pos] = (unsigned int)src[e] | ((unsigned int)(d & 1023) << 17);
    }
}

// ---------------- pass D — per-(bucket,rel) fine CSR ----------------
__global__ __launch_bounds__(256) void csr_fine_kernel(
    const unsigned int* __restrict__ ebuf, const int* __restrict__ bbase,
    int* __restrict__ row_ptr, float* __restrict__ inv_deg, int* __restrict__ col_idx)
{
    __shared__ int nh[1024];
    __shared__ int nb[1024];
    __shared__ int wsum4[4];
    __shared__ int stage[STCAP];
    int r = blockIdx.y, b = blockIdx.x;
    int tid = threadIdx.x, lane = tid & 63, wid = tid >> 6;
    int gb = bbase[r * (NBK + 1) + b];
    int ge = bbase[r * (NBK + 1) + b + 1];
    int cnt = ge - gb;
    if (cnt > STCAP) cnt = STCAP;
    const unsigned int* eb = ebuf + (size_t)r * EE + gb;
    #pragma unroll
    for (int j = 0; j < 4; ++j) nh[tid * 4 + j] = 0;
    __syncthreads();
    for (int i = tid; i < cnt; i += 256)
        atomicAdd(&nh[(eb[i] >> 17) & 1023], 1);
    __syncthreads();
    int v0 = nh[tid * 4 + 0], v1 = nh[tid * 4 + 1], v2 = nh[tid * 4 + 2], v3 = nh[tid * 4 + 3];
    int s = v0 + v1 + v2 + v3;
    int si = s;
    #pragma unroll
    for (int off = 1; off < 64; off <<= 1) {
        int t = __shfl_up(si, off);
        if (lane >= off) si += t;
    }
    if (lane == 63) wsum4[wid] = si;
    __syncthreads();
    if (tid == 0) {
        int a = 0;
        #pragma unroll
        for (int k = 0; k < 4; ++k) { int t = wsum4[k]; wsum4[k] = a; a += t; }
    }
    __syncthreads();
    int texcl = wsum4[wid] + (si - s);
    int p0 = texcl, p1 = p0 + v0, p2 = p1 + v1, p3 = p2 + v2;
    nb[tid * 4 + 0] = p0; nb[tid * 4 + 1] = p1; nb[tid * 4 + 2] = p2; nb[tid * 4 + 3] = p3;
    {
        int node0 = b * 1024 + tid * 4;
        int pj[4] = { p0, p1, p2, p3 };
        int vj[4] = { v0, v1, v2, v3 };
        #pragma unroll
        for (int j = 0; j < 4; ++j) {
            int node = node0 + j;
            if (node < NN) {
                row_ptr[r * (NN + 1) + node] = gb + pj[j];
                inv_deg[r * NN + node] = 1.0f / (float)(vj[j] > 1 ? vj[j] : 1);
            }
        }
    }
    if (b == NBK - 1 && tid == 0) row_ptr[r * (NN + 1) + NN] = EE;
    #pragma unroll
    for (int j = 0; j < 4; ++j) nh[tid * 4 + j] = 0;
    __syncthreads();
    for (int i = tid; i < cnt; i += 256) {
        unsigned int w = eb[i];
        int loc = (w >> 17) & 1023;
        int pos = nb[loc] + atomicAdd(&nh[loc], 1);
        stage[pos] = (int)(w & 0x1ffffu);
    }
    __syncthreads();
    int* co = col_idx + (size_t)r * EE + gb;
    for (int i = tid; i < cnt; i += 256) co[i] = stage[i];
}

// ---------------- bucket-local sum-degree sort: vr 0 = dstA {1,2,5}, vr 1 = dstB {0,3,4} ----------------
__device__ __forceinline__ int sdeg(int vr, int n, const int* __restrict__ rp)
{
    if (vr == 0)
        return (rp[1 * (NN + 1) + n + 1] - rp[1 * (NN + 1) + n])
             + (rp[2 * (NN + 1) + n + 1] - rp[2 * (NN + 1) + n])
             + (rp[5 * (NN + 1) + n + 1] - rp[5 * (NN + 1) + n]);
    return (rp[0 * (NN + 1) + n + 1] - rp[0 * (NN + 1) + n])
         + (rp[3 * (NN + 1) + n + 1] - rp[3 * (NN + 1) + n])
         + (rp[4 * (NN + 1) + n + 1] - rp[4 * (NN + 1) + n]);
}

__global__ __launch_bounds__(256) void bsort_kernel(
    const int* __restrict__ row_ptr, int* __restrict__ perm, int* __restrict__ iperm)
{
    __shared__ int h[DBIN];
    __shared__ int base_[DBIN];
    int vr = blockIdx.y, b = blockIdx.x;
    int n0 = b * 1024;
    int cnt = min(1024, NN - n0);
    int tid = threadIdx.x;
    if (tid < DBIN) h[tid] = 0;
    __syncthreads();
    int bin[4];
    #pragma unroll
    for (int j = 0; j < 4; ++j) {
        int i = tid + j * 256;
        if (i < cnt) {
            bin[j] = min(sdeg(vr, n0 + i, row_ptr), DBIN - 1);
            atomicAdd(&h[bin[j]], 1);
        } else bin[j] = -1;
    }
    __syncthreads();
    if (tid < 64) {
        int v = h[tid];
        int s = v;
        #pragma unroll
        for (int off = 1; off < 64; off <<= 1) {
            int t = __shfl_up(s, off);
            if (tid >= off) s += t;
        }
        base_[tid] = s - v;
        h[tid] = 0;
    }
    __syncthreads();
    #pragma unroll
    for (int j = 0; j < 4; ++j) {
        if (bin[j] >= 0) {
            int n = n0 + tid + j * 256;
            int pos = n0 + base_[bin[j]] + atomicAdd(&h[bin[j]], 1);
            perm[vr * NN + pos] = n;
            iperm[vr * NN + n] = pos;
        }
    }
}

// ---------------- translate col_idx in place through iperm of the src side ----------------
__global__ __launch_bounds__(256) void translate_kernel(
    const int* __restrict__ iperm, int* __restrict__ col_idx)
{
    const int srcSide[NR] = {0, 1, 0, 1, 0, 1};   // A=0, B=1
    int r = blockIdx.y;
    const int* ip = iperm + srcSide[r] * NN;
    int* ci = col_idx + (size_t)r * EE;
    for (int e = blockIdx.x * 256 + threadIdx.x; e < EE; e += gridDim.x * 256)
        ci[e] = ip[ci[e]];
}

// ---------------- embeddings -> bf16, stored in permuted (processing) order ----------------
__global__ __launch_bounds__(256) void cvtp_kernel(
    const float* __restrict__ inA, const float* __restrict__ inB,
    const int* __restrict__ perm, ushort* __restrict__ outA, ushort* __restrict__ outB)
{
    int side = blockIdx.y;
    int t = blockIdx.x * 256 + threadIdx.x;
    if (t >= NN * 8) return;
    int idx = t >> 3, j = t & 7;
    int n = perm[side * NN + idx];
    const float* in = side ? inB : inA;
    ushort* out = side ? outB : outA;
    float4 v0 = ((const float4*)in)[n * 16 + j * 2];
    float4 v1 = ((const float4*)in)[n * 16 + j * 2 + 1];
    int4 o;
    o.x = (int)((unsigned int)f2bf(v0.x) | ((unsigned int)f2bf(v0.y) << 16));
    o.y = (int)((unsigned int)f2bf(v0.z) | ((unsigned int)f2bf(v0.w) << 16));
    o.z = (int)((unsigned int)f2bf(v1.x) | ((unsigned int)f2bf(v1.y) << 16));
    o.w = (int)((unsigned int)f2bf(v1.z) | ((unsigned int)f2bf(v1.w) << 16));
    *(int4*)(out + (size_t)idx * DD + j * 8) = o;
}

// ---------------- fused layer-0: gather 3 rels + bias + relu -> h0p (sequential write) ----------------
__global__ __launch_bounds__(256) void layer0_kernel(
    const ushort* __restrict__ eA, const ushort* __restrict__ eB,
    const int* __restrict__ row_ptr, const int* __restrict__ col_idx,
    const float* __restrict__ inv_deg, const int* __restrict__ perm,
    const float* __restrict__ bias, ushort* __restrict__ hA, ushort* __restrict__ hB)
{
    int side = blockIdx.y;
    const int relT[2][3] = { {1, 2, 5}, {0, 3, 4} };
    int tid = threadIdx.x;
    int wid = tid >> 6, lane = tid & 63;
    int grp = lane >> 3, sub = lane & 7;
    int idx = blockIdx.x * 32 + wid * 8 + grp;
    bool valid = (idx < NN);
    int n = valid ? perm[side * NN + idx] : 0;
    float acc[8];
    {
        float4 b0 = *(const float4*)(bias + sub * 8);
        float4 b1 = *(const float4*)(bias + sub * 8 + 4);
        acc[0] = b0.x; acc[1] = b0.y; acc[2] = b0.z; acc[3] = b0.w;
        acc[4] = b1.x; acc[5] = b1.y; acc[6] = b1.z; acc[7] = b1.w;
    }
    #pragma unroll
    for (int ks = 0; ks < 3; ++ks) {
        int r = relT[side][ks];
        const ushort* F = ((side == 0) == (ks == 1)) ? eA : eB;
        const int* rp = row_ptr + r * (NN + 1);
        const int* ci = col_idx + (size_t)r * EE;
        int s = valid ? rp[n] : 0;
        int e = valid ? rp[n + 1] : 0;
        float a0 = 0.f, a1 = 0.f, a2 = 0.f, a3 = 0.f, a4 = 0.f, a5 = 0.f, a6 = 0.f, a7 = 0.f;
        int t = s;
        for (; t + 2 <= e; t += 2) {
            int c0 = ci[t], c1 = ci[t + 1];
            int4 u = *(const int4*)(F + (size_t)c0 * DD + sub * 8);
            int4 w = *(const int4*)(F + (size_t)c1 * DD + sub * 8);
            float l, h;
            bfpair((unsigned int)u.x, l, h); a0 += l; a1 += h;
            bfpair((unsigned int)u.y, l, h); a2 += l; a3 += h;
            bfpair((unsigned int)u.z, l, h); a4 += l; a5 += h;
            bfpair((unsigned int)u.w, l, h); a6 += l; a7 += h;
            bfpair((unsigned int)w.x, l, h); a0 += l; a1 += h;
            bfpair((unsigned int)w.y, l, h); a2 += l; a3 += h;
            bfpair((unsigned int)w.z, l, h); a4 += l; a5 += h;
            bfpair((unsigned int)w.w, l, h); a6 += l; a7 += h;
        }
        if (t < e) {
            int4 u = *(const int4*)(F + (size_t)ci[t] * DD + sub * 8);
            float l, h;
            bfpair((unsigned int)u.x, l, h); a0 += l; a1 += h;
            bfpair((unsigned int)u.y, l, h); a2 += l; a3 += h;
            bfpair((unsigned int)u.z, l, h); a4 += l; a5 += h;
            bfpair((unsigned int)u.w, l, h); a6 += l; a7 += h;
        }
        float inv = valid ? inv_deg[r * NN + n] : 0.f;
        acc[0] += a0 * inv; acc[1] += a1 * inv; acc[2] += a2 * inv; acc[3] += a3 * inv;
        acc[4] += a4 * inv; acc[5] += a5 * inv; acc[6] += a6 * inv; acc[7] += a7 * inv;
    }
    if (valid) {
        ushort* h = side ? hB : hA;
        int4 o;
        o.x = (int)((unsigned int)f2bf(fmaxf(acc[0], 0.f)) | ((unsigned int)f2bf(fmaxf(acc[1], 0.f)) << 16));
        o.y = (int)((unsigned int)f2bf(fmaxf(acc[2], 0.f)) | ((unsigned int)f2bf(fmaxf(acc[3], 0.f)) << 16));
        o.z = (int)((unsigned int)f2bf(fmaxf(acc[4], 0.f)) | ((unsigned int)f2bf(fmaxf(acc[5], 0.f)) << 16));
        o.w = (int)((unsigned int)f2bf(fmaxf(acc[6], 0.f)) | ((unsigned int)f2bf(fmaxf(acc[7], 0.f)) << 16));
        *(int4*)(h + (size_t)idx * DD + sub * 8) = o;     // sequential by idx
    }
}

// ---------------- fused layer-1: gather -> LDS -> MFMA(h1) -> MFMA(y2 = h1 @ W2) -> y2 tables ----------------
// y2 slot tables (indexed in src-side permuted idx space): slot0 = h1B@W2[1], slot1 = h1A@W2[2], slot2 = h1B@W2[5]
__global__ __launch_bounds__(256) void layer1_fused_kernel(
    const ushort* __restrict__ h0A, const ushort* __restrict__ h0B,
    const int* __restrict__ row_ptr, const int* __restrict__ col_idx,
    const float* __restrict__ inv_deg, const int* __restrict__ perm,
    const ushort* __restrict__ Wp, const ushort* __restrict__ Wp2,
    const float* __restrict__ bias, ushort* __restrict__ y2)
{
    __shared__ unsigned int sZ[32 * LROW];   // 12.8 KB; reused as bf16 C-stage
    int side = blockIdx.y;
    const int relT[2][3] = { {1, 2, 5}, {0, 3, 4} };
    int tid = threadIdx.x;
    int wid = tid >> 6, lane = tid & 63;
    int grp = lane >> 3, sub = lane & 7;
    int ln = wid * 8 + grp;
    int idx0 = blockIdx.x * 32;
    int idx = idx0 + ln;
    bool valid = (idx < NN);
    int n = valid ? perm[side * NN + idx] : 0;
    #pragma unroll
    for (int ks = 0; ks < 3; ++ks) {
        int r = relT[side][ks];
        const ushort* F = ((side == 0) == (ks == 1)) ? h0A : h0B;
        const int* rp = row_ptr + r * (NN + 1);
        const int* ci = col_idx + (size_t)r * EE;
        int s = valid ? rp[n] : 0;
        int e = valid ? rp[n + 1] : 0;
        float a0 = 0.f, a1 = 0.f, a2 = 0.f, a3 = 0.f, a4 = 0.f, a5 = 0.f, a6 = 0.f, a7 = 0.f;
        int t = s;
        for (; t + 2 <= e; t += 2) {
            int c0 = ci[t], c1 = ci[t + 1];
            int4 u = *(const int4*)(F + (size_t)c0 * DD + sub * 8);
            int4 w = *(const int4*)(F + (size_t)c1 * DD + sub * 8);
            float l, h;
            bfpair((unsigned int)u.x, l, h); a0 += l; a1 += h;
            bfpair((unsigned int)u.y, l, h); a2 += l; a3 += h;
            bfpair((unsigned int)u.z, l, h); a4 += l; a5 += h;
            bfpair((unsigned int)u.w, l, h); a6 += l; a7 += h;
            bfpair((unsigned int)w.x, l, h); a0 += l; a1 += h;
            bfpair((unsigned int)w.y, l, h); a2 += l; a3 += h;
            bfpair((unsigned int)w.z, l, h); a4 += l; a5 += h;
            bfpair((unsigned int)w.w, l, h); a6 += l; a7 += h;
        }
        if (t < e) {
            int4 u = *(const int4*)(F + (size_t)ci[t] * DD + sub * 8);
            float l, h;
            bfpair((unsigned int)u.x, l, h); a0 += l; a1 += h;
            bfpair((unsigned int)u.y, l, h); a2 += l; a3 += h;
            bfpair((unsigned int)u.z, l, h); a4 += l; a5 += h;
            bfpair((unsigned int)u.w, l, h); a6 += l; a7 += h;
        }
        float inv = valid ? inv_deg[r * NN + n] : 0.f;
        int4 o;
        o.x = (int)((unsigned int)f2bf(a0 * inv) | ((unsigned int)f2bf(a1 * inv) << 16));
        o.y = (int)((unsigned int)f2bf(a2 * inv) | ((unsigned int)f2bf(a3 * inv) << 16));
        o.z = (int)((unsigned int)f2bf(a4 * inv) | ((unsigned int)f2bf(a5 * inv) << 16));
        o.w = (int)((unsigned int)f2bf(a6 * inv) | ((unsigned int)f2bf(a7 * inv) << 16));
        *(int4*)&sZ[ln * LROW + ks * 32 + sub * 4] = o;
    }
    __syncthreads();
    // MFMA 1: h1 rows. wave -> 16 rows x 32 cols
    int q = lane & 15, p = lane >> 4;
    int base16 = (wid >> 1) * 16, cb = (wid & 1) * 32;
    f32x4 acc0 = {0.f, 0.f, 0.f, 0.f};
    f32x4 acc1 = {0.f, 0.f, 0.f, 0.f};
    #pragma unroll
    for (int ks = 0; ks < 3; ++ks) {
        int rel = relT[side][ks];
        #pragma unroll
        for (int tt = 0; tt < 2; ++tt) {
            int4 t4 = *(const int4*)&sZ[(base16 + q) * LROW + (ks * 2 + tt) * 16 + p * 4];
            bf16x8 a = *(const bf16x8*)&t4;
            const ushort* wb = Wp + (((size_t)(rel * 8 + tt * 4 + p) * 64 + cb + q) << 3);
            bf16x8 b0 = *(const bf16x8*)wb;
            bf16x8 b1 = *(const bf16x8*)(wb + 16 * 8);
            acc0 = __builtin_amdgcn_mfma_f32_16x16x32_bf16(a, b0, acc0, 0, 0, 0);
            acc1 = __builtin_amdgcn_mfma_f32_16x16x32_bf16(a, b1, acc1, 0, 0, 0);
        }
    }
    __syncthreads();
    ushort* sC = (ushort*)sZ;
    {
        float bv0 = bias[cb + q], bv1 = bias[cb + 16 + q];
        #pragma unroll
        for (int v = 0; v < 4; ++v) {
            int row = base16 + p * 4 + v;
            sC[row * 64 + cb + q]      = f2bf(fmaxf(acc0[v] + bv0, 0.f));
            sC[row * 64 + cb + 16 + q] = f2bf(fmaxf(acc1[v] + bv1, 0.f));
        }
    }
    __syncthreads();
    // MFMA 2: y2 = h1(sC rows) @ W2_rel -> global y2 slot tables (h1 itself never hits global)
    // side 0 (h1A): slot1/rel2, waves 0-1. side 1 (h1B): slot0/rel1 waves 0-1, slot2/rel5 waves 2-3.
    int yb16, rel2_, slot;
    bool doy;
    if (side == 0) { doy = (wid < 2); yb16 = wid * 16;        rel2_ = 2;                    slot = 1; }
    else           { doy = true;      yb16 = (wid & 1) * 16;  rel2_ = (wid >> 1) ? 5 : 1;   slot = (wid >> 1) ? 2 : 0; }
    if (doy) {
        f32x4 yacc = {0.f, 0.f, 0.f, 0.f};
        #pragma unroll
        for (int tt = 0; tt < 2; ++tt) {
            bf16x8 a = *(const bf16x8*)(sC + (yb16 + q) * 64 + tt * 32 + p * 8);
            bf16x8 b = *(const bf16x8*)(Wp2 + (((size_t)(rel2_ * 8 + tt * 4 + p) * 16 + q) << 3));
            yacc = __builtin_amdgcn_mfma_f32_16x16x32_bf16(a, b, yacc, 0, 0, 0);
        }
        ushort* Y = y2 + (size_t)slot * NN * OD;
        #pragma unroll
        for (int v = 0; v < 4; ++v) {
            int row = yb16 + p * 4 + v;
            if (idx0 + row < NN) Y[(size_t)(idx0 + row) * OD + q] = f2bf(yacc[v]);
        }
    }
}

// ---------------- layer-2: light 32B/edge gather from y2 tables + bias -> d_out (f32) ----------------
__global__ __launch_bounds__(256) void layer2_gather_kernel(
    const ushort* __restrict__ y2,
    const int* __restrict__ row_ptr, const int* __restrict__ col_idx,
    const float* __restrict__ inv_deg, const int* __restrict__ perm,
    const float* __restrict__ bias, float* __restrict__ out)
{
    const int rr0 = 1, rr1 = 2, rr2 = 5;
    const ushort* Y0 = y2;
    const ushort* Y1 = y2 + (size_t)NN * OD;
    const ushort* Y2 = y2 + (size_t)2 * NN * OD;
    int tid = threadIdx.x;
    int wid = tid >> 6, lane = tid & 63;
    int grp = lane >> 3, sub = lane & 7;
    int idx = blockIdx.x * 32 + wid * 8 + grp;
    if (idx >= NN) return;
    int n = perm[idx];
    float o0 = 0.f, o1 = 0.f;
    #pragma unroll
    for (int ks = 0; ks < 3; ++ks) {
        int r = (ks == 0) ? rr0 : ((ks == 1) ? rr1 : rr2);
        const ushort* Y = (ks == 0) ? Y0 : ((ks == 1) ? Y1 : Y2);
        const int* rp = row_ptr + r * (NN + 1);
        const int* ci = col_idx + (size_t)r * EE;
        int s = rp[n], e = rp[n + 1];
        float a0 = 0.f, a1 = 0.f;
        int t = s;
        for (; t + 2 <= e; t += 2) {
            unsigned int u = *(const unsigned int*)(Y + (size_t)ci[t] * OD + sub * 2);
            unsigned int w = *(const unsigned int*)(Y + (size_t)ci[t + 1] * OD + sub * 2);
            float l, h;
            bfpair(u, l, h); a0 += l; a1 += h;
            bfpair(w, l, h); a0 += l; a1 += h;
        }
        if (t < e) {
            unsigned int u = *(const unsigned int*)(Y + (size_t)ci[t] * OD + sub * 2);
            float l, h;
            bfpair(u, l, h); a0 += l; a1 += h;
        }
        float inv = inv_deg[r * NN + n];
        o0 += a0 * inv; o1 += a1 * inv;
    }
    float2 ov;
    ov.x = o0 + bias[sub * 2];
    ov.y = o1 + bias[sub * 2 + 1];
    *(float2*)(out + (size_t)n * OD + sub * 2) = ov;
}

extern "C" void kernel_launch(void* const* d_in, const int* in_sizes, int n_in,
                              void* d_out, int out_size, void* d_ws, size_t ws_size,
                              hipStream_t stream)
{
    const float* embA  = (const float*)d_in[0];
    const float* embB  = (const float*)d_in[1];
    const float* bias0 = (const float*)d_in[2];
    const float* wc1   = (const float*)d_in[3];
    const float* b1    = (const float*)d_in[4];
    const float* bias1 = (const float*)d_in[5];
    const float* wc2   = (const float*)d_in[6];
    const float* b2    = (const float*)d_in[7];
    const float* bias2 = (const float*)d_in[8];

    Edges ep;
    for (int r = 0; r < NR; ++r) {
        ep.src[r] = (const int*)d_in[9 + 2 * r];
        ep.dst[r] = (const int*)d_in[10 + 2 * r];
    }

    char* ws = (char*)d_ws;
    size_t off = 0;
    auto alloc = [&](size_t bytes) {
        void* p = ws + off;
        off = (off + bytes + 255) & ~(size_t)255;
        return p;
    };
    ushort* Wp1     = (ushort*)alloc((size_t)NR * 8 * 64 * 8 * 2);
    ushort* Wp2     = (ushort*)alloc((size_t)NR * 8 * 16 * 8 * 2);
    int*    cnt_mat = (int*)   alloc((size_t)NR * FLATN * 4);
    int*    off_fl  = (int*)   alloc((size_t)NR * FLATN * 4);
    int*    bbase   = (int*)   alloc((size_t)NR * (NBK + 1) * 4);
    int*    row_ptr = (int*)   alloc((size_t)NR * (NN + 1) * 4);
    float*  inv_deg = (float*) alloc((size_t)NR * NN * 4);
    int*    col_idx = (int*)   alloc((size_t)NR * EE * 4);
    int*    perm    = (int*)   alloc((size_t)2 * NN * 4);
    int*    iperm   = (int*)   alloc((size_t)2 * NN * 4);
    ushort* reg1    = (ushort*)alloc((size_t)2 * NN * DD * 2);   // ebuf -> embp -> y2
    ushort* h0pA    = (ushort*)alloc((size_t)NN * DD * 2);
    ushort* h0pB    = (ushort*)alloc((size_t)NN * DD * 2);
    (void)ws_size;

    // lifetime-disjoint aliases inside reg1 (25.6 MB):
    unsigned int* ebuf  = (unsigned int*)reg1;       // dead after csr_fine
    ushort*       embpA = reg1;                      // written by cvtp (after csr_fine), dead after layer0
    ushort*       embpB = reg1 + (size_t)NN * DD;
    ushort*       y2buf = reg1;                      // 3 * NN * 16 * 2B = 9.6 MB, written by layer1

    int nw = NR * DD * DD + NR * DD * OD;
    build_w_kernel<<<(nw + 255) / 256, 256, 0, stream>>>(wc1, b1, wc2, b2, Wp1, Wp2);

    count_kernel<<<dim3(SBLK, NR), 256, 0, stream>>>(ep, cnt_mat);
    flat_scan_kernel<<<NR, 1024, 0, stream>>>(cnt_mat, off_fl, bbase);
    scatter2_kernel<<<dim3(SBLK, NR), 256, 0, stream>>>(ep, off_fl, ebuf);
    csr_fine_kernel<<<dim3(NBK, NR), 256, 0, stream>>>(ebuf, bbase, row_ptr, inv_deg, col_idx);

    bsort_kernel<<<dim3(NBK, 2), 256, 0, stream>>>(row_ptr, perm, iperm);
    translate_kernel<<<dim3(64, NR), 256, 0, stream>>>(iperm, col_idx);
    cvtp_kernel<<<dim3((NN * 8 + 255) / 256, 2), 256, 0, stream>>>(
        embA, embB, perm, embpA, embpB);

    int agx = (NN + 31) / 32;
    // relations: r0 A->B, r1 B->A, r2 A->A, r3 B->B, r4 A->B, r5 B->A
    // dst A: rels {1,2,5} srcs {B,A,B};  dst B: rels {0,3,4} srcs {A,B,A}

    layer0_kernel<<<dim3(agx, 2), 256, 0, stream>>>(
        embpA, embpB, row_ptr, col_idx, inv_deg, perm, bias0, h0pA, h0pB);

    layer1_fused_kernel<<<dim3(agx, 2), 256, 0, stream>>>(
        h0pA, h0pB, row_ptr, col_idx, inv_deg, perm, Wp1, Wp2, bias1, y2buf);

    layer2_gather_kernel<<<agx, 256, 0, stream>>>(
        y2buf, row_ptr, col_idx, inv_deg, perm, bias2, (float*)d_out);
}

// Round 14
// 294.160 us; speedup vs baseline: 1.2233x; 1.0223x over previous
//
#include <hip/hip_runtime.h>

#define NN 100000
#define EE 500000
#define DD 64
#define OD 16
#define NR 6
#define NBASE 4
#define BSH 10
#define NBK 98         /* ceil(NN / 1024) */
#define SBLK 128       /* scatter blocks per relation */
#define FLATN (NBK * SBLK)   /* 12544 */
#define STCAP 5632     /* fine-bucket edge capacity */
#define DBIN 64        /* degree-sort bins */
#define LROW 100       /* LDS row stride in dwords (padded, 16B-aligned) */

struct Edges { const int* src[NR]; const int* dst[NR]; };

typedef __attribute__((ext_vector_type(8))) short bf16x8;
typedef __attribute__((ext_vector_type(4))) float f32x4;

__device__ __forceinline__ float bf2f(ushort u) {
    union { unsigned int i; float f; } v; v.i = ((unsigned int)u) << 16; return v.f;
}
__device__ __forceinline__ ushort f2bf(float f) {
    unsigned int x = __float_as_uint(f);
    unsigned int r = (x + 0x7fffu + ((x >> 16) & 1u)) >> 16;
    return (ushort)r;
}
__device__ __forceinline__ void bfpair(unsigned int u, float& lo, float& hi) {
    lo = __uint_as_float(u << 16);
    hi = __uint_as_float(u & 0xffff0000u);
}
__device__ __forceinline__ void acc8(const int4& u, float* a) {
    float l, h;
    bfpair((unsigned int)u.x, l, h); a[0] += l; a[1] += h;
    bfpair((unsigned int)u.y, l, h); a[2] += l; a[3] += h;
    bfpair((unsigned int)u.z, l, h); a[4] += l; a[5] += h;
    bfpair((unsigned int)u.w, l, h); a[6] += l; a[7] += h;
}

// gather-sum rows [s,e): 4 independent 16B loads in flight per iteration
__device__ __forceinline__ void gatherrow(
    const ushort* __restrict__ F, const int* __restrict__ ci,
    int s, int e, int sub, float* a)
{
    int t = s;
    for (; t + 4 <= e; t += 4) {
        int c0 = ci[t], c1 = ci[t + 1], c2 = ci[t + 2], c3 = ci[t + 3];
        int4 u0 = *(const int4*)(F + (size_t)c0 * DD + sub * 8);
        int4 u1 = *(const int4*)(F + (size_t)c1 * DD + sub * 8);
        int4 u2 = *(const int4*)(F + (size_t)c2 * DD + sub * 8);
        int4 u3 = *(const int4*)(F + (size_t)c3 * DD + sub * 8);
        acc8(u0, a); acc8(u1, a); acc8(u2, a); acc8(u3, a);
    }
    for (; t < e; ++t) {
        int4 u = *(const int4*)(F + (size_t)ci[t] * DD + sub * 8);
        acc8(u, a);
    }
}

// ---------------- W = einsum('rb,bio->rio'), emitted bf16 B-fragment-packed ----------------
__global__ __launch_bounds__(256) void build_w_kernel(
    const float* __restrict__ wc1, const float* __restrict__ b1,
    const float* __restrict__ wc2, const float* __restrict__ b2,
    ushort* __restrict__ Wp1, ushort* __restrict__ Wp2)
{
    int idx = blockIdx.x * blockDim.x + threadIdx.x;
    const int n1 = NR * DD * DD;
    const int n2 = NR * DD * OD;
    if (idx < n1) {
        int r = idx >> 12, rem = idx & 4095;
        int i = rem >> 6, o = rem & 63;
        float s = 0.f;
        #pragma unroll
        for (int b = 0; b < NBASE; ++b) s += wc1[r * NBASE + b] * b1[b * 4096 + rem];
        Wp1[(((size_t)(r * 8 + (i >> 3)) * 64 + o) << 3) + (i & 7)] = f2bf(s);
    } else if (idx < n1 + n2) {
        int j = idx - n1;
        int r = j >> 10, rem = j & 1023;
        int i = rem >> 4, o = rem & 15;
        float s = 0.f;
        #pragma unroll
        for (int b = 0; b < NBASE; ++b) s += wc2[r * NBASE + b] * b2[b * 1024 + rem];
        Wp2[(((size_t)(r * 8 + (i >> 3)) * 16 + o) << 3) + (i & 7)] = f2bf(s);
    }
}

// ---------------- CSR build: pass A — per-(block,bucket) counts ----------------
__global__ __launch_bounds__(256) void count_kernel(Edges ep, int* __restrict__ cnt_mat)
{
    __shared__ int h[NBK];
    int r = blockIdx.y, blk = blockIdx.x;
    const int* __restrict__ dst = ep.dst[r];
    const int chunk = (EE + SBLK - 1) / SBLK;
    int e0 = blk * chunk, e1 = min(e0 + chunk, EE);
    for (int i = threadIdx.x; i < NBK; i += 256) h[i] = 0;
    __syncthreads();
    for (int e = e0 + threadIdx.x; e < e1; e += 256)
        atomicAdd(&h[dst[e] >> BSH], 1);
    __syncthreads();
    for (int b = threadIdx.x; b < NBK; b += 256)
        cnt_mat[r * FLATN + b * SBLK + blk] = h[b];
}

// ---------------- pass B — flat exclusive scan over (bucket, block) per rel ----------------
__global__ __launch_bounds__(1024) void flat_scan_kernel(
    const int* __restrict__ cnt_mat, int* __restrict__ off_flat, int* __restrict__ bbase)
{
    __shared__ int wsum[16];
    const int TPE = 13;
    int r = blockIdx.x;
    int tid = threadIdx.x, lane = tid & 63, wid = tid >> 6;
    int base = tid * TPE;
    int v[TPE];
    int s = 0;
    #pragma unroll
    for (int j = 0; j < TPE; ++j) {
        int i = base + j;
        v[j] = (i < FLATN) ? cnt_mat[r * FLATN + i] : 0;
        s += v[j];
    }
    int si = s;
    #pragma unroll
    for (int off = 1; off < 64; off <<= 1) {
        int t = __shfl_up(si, off);
        if (lane >= off) si += t;
    }
    if (lane == 63) wsum[wid] = si;
    __syncthreads();
    if (wid == 0) {
        int ws = (lane < 16) ? wsum[lane] : 0;
        #pragma unroll
        for (int off = 1; off < 16; off <<= 1) {
            int t = __shfl_up(ws, off);
            if (lane >= off) ws += t;
        }
        if (lane < 16) wsum[lane] = ws;
    }
    __syncthreads();
    int texcl = (wid > 0 ? wsum[wid - 1] : 0) + (si - s);
    int part = 0;
    #pragma unroll
    for (int j = 0; j < TPE; ++j) {
        int i = base + j;
        if (i < FLATN) {
            int o = texcl + part;
            off_flat[r * FLATN + i] = o;
            if ((i & (SBLK - 1)) == 0) bbase[r * (NBK + 1) + (i >> 7)] = o;
        }
        part += v[j];
    }
    if (tid == 0) bbase[r * (NBK + 1) + NBK] = EE;
}

// ---------------- pass C — scatter with precomputed cursors ----------------
__global__ __launch_bounds__(256) void scatter2_kernel(
    Edges ep, const int* __restrict__ off_flat, unsigned int* __restrict__ ebuf)
{
    __shared__ int goff[NBK];
    __shared__ int lcnt[NBK];
    int r = blockIdx.y, blk = blockIdx.x;
    const int* __restrict__ src = ep.src[r];
    const int* __restrict__ dst = ep.dst[r];
    unsigned int* eb = ebuf + (size_t)r * EE;
    const int chunk = (EE + SBLK - 1) / SBLK;
    int e0 = blk * chunk, e1 = min(e0 + chunk, EE);
    if (threadIdx.x < NBK) {
        goff[threadIdx.x] = off_flat[r * FLATN + threadIdx.x * SBLK + blk];
        lcnt[threadIdx.x] = 0;
    }
    __syncthreads();
    for (int e = e0 + threadIdx.x; e < e1; e += 256) {
        int d = dst[e];
        int b = d >> BSH;
        int pos = goff[b] + atomicAdd(&lcnt[b], 1);
        eb[pos] = (unsigned int)src[e] | ((unsigned int)(d & 1023) << 17);
    }
}

// ---------------- pass D — per-(bucket,rel) fine CSR ----------------
__global__ __launch_bounds__(256) void csr_fine_kernel(
    const unsigned int* __restrict__ ebuf, const int* __restrict__ bbase,
    int* __restrict__ row_ptr, float* __restrict__ inv_deg, int* __restrict__ col_idx)
{
    __shared__ int nh[1024];
    __shared__ int nb[1024];
    __shared__ int wsum4[4];
    __shared__ int stage[STCAP];
    int r = blockIdx.y, b = blockIdx.x;
    int tid = threadIdx.x, lane = tid & 63, wid = tid >> 6;
    int gb = bbase[r * (NBK + 1) + b];
    int ge = bbase[r * (NBK + 1) + b + 1];
    int cnt = ge - gb;
    if (cnt > STCAP) cnt = STCAP;
    const unsigned int* eb = ebuf + (size_t)r * EE + gb;
    #pragma unroll
    for (int j = 0; j < 4; ++j) nh[tid * 4 + j] = 0;
    __syncthreads();
    for (int i = tid; i < cnt; i += 256)
        atomicAdd(&nh[(eb[i] >> 17) & 1023], 1);
    __syncthreads();
    int v0 = nh[tid * 4 + 0], v1 = nh[tid * 4 + 1], v2 = nh[tid * 4 + 2], v3 = nh[tid * 4 + 3];
    int s = v0 + v1 + v2 + v3;
    int si = s;
    #pragma unroll
    for (int off = 1; off < 64; off <<= 1) {
        int t = __shfl_up(si, off);
        if (lane >= off) si += t;
    }
    if (lane == 63) wsum4[wid] = si;
    __syncthreads();
    if (tid == 0) {
        int a = 0;
        #pragma unroll
        for (int k = 0; k < 4; ++k) { int t = wsum4[k]; wsum4[k] = a; a += t; }
    }
    __syncthreads();
    int texcl = wsum4[wid] + (si - s);
    int p0 = texcl, p1 = p0 + v0, p2 = p1 + v1, p3 = p2 + v2;
    nb[tid * 4 + 0] = p0; nb[tid * 4 + 1] = p1; nb[tid * 4 + 2] = p2; nb[tid * 4 + 3] = p3;
    {
        int node0 = b * 1024 + tid * 4;
        int pj[4] = { p0, p1, p2, p3 };
        int vj[4] = { v0, v1, v2, v3 };
        #pragma unroll
        for (int j = 0; j < 4; ++j) {
            int node = node0 + j;
            if (node < NN) {
                row_ptr[r * (NN + 1) + node] = gb + pj[j];
                inv_deg[r * NN + node] = 1.0f / (float)(vj[j] > 1 ? vj[j] : 1);
            }
        }
    }
    if (b == NBK - 1 && tid == 0) row_ptr[r * (NN + 1) + NN] = EE;
    #pragma unroll
    for (int j = 0; j < 4; ++j) nh[tid * 4 + j] = 0;
    __syncthreads();
    for (int i = tid; i < cnt; i += 256) {
        unsigned int w = eb[i];
        int loc = (w >> 17) & 1023;
        int pos = nb[loc] + atomicAdd(&nh[loc], 1);
        stage[pos] = (int)(w & 0x1ffffu);
    }
    __syncthreads();
    int* co = col_idx + (size_t)r * EE + gb;
    for (int i = tid; i < cnt; i += 256) co[i] = stage[i];
}

// ---------------- bucket-local sum-degree sort: vr 0 = dstA {1,2,5}, vr 1 = dstB {0,3,4} ----------------
__device__ __forceinline__ int sdeg(int vr, int n, const int* __restrict__ rp)
{
    if (vr == 0)
        return (rp[1 * (NN + 1) + n + 1] - rp[1 * (NN + 1) + n])
             + (rp[2 * (NN + 1) + n + 1] - rp[2 * (NN + 1) + n])
             + (rp[5 * (NN + 1) + n + 1] - rp[5 * (NN + 1) + n]);
    return (rp[0 * (NN + 1) + n + 1] - rp[0 * (NN + 1) + n])
         + (rp[3 * (NN + 1) + n + 1] - rp[3 * (NN + 1) + n])
         + (rp[4 * (NN + 1) + n + 1] - rp[4 * (NN + 1) + n]);
}

__global__ __launch_bounds__(256) void bsort_kernel(
    const int* __restrict__ row_ptr, int* __restrict__ perm, int* __restrict__ iperm)
{
    __shared__ int h[DBIN];
    __shared__ int base_[DBIN];
    int vr = blockIdx.y, b = blockIdx.x;
    int n0 = b * 1024;
    int cnt = min(1024, NN - n0);
    int tid = threadIdx.x;
    if (tid < DBIN) h[tid] = 0;
    __syncthreads();
    int bin[4];
    #pragma unroll
    for (int j = 0; j < 4; ++j) {
        int i = tid + j * 256;
        if (i < cnt) {
            bin[j] = min(sdeg(vr, n0 + i, row_ptr), DBIN - 1);
            atomicAdd(&h[bin[j]], 1);
        } else bin[j] = -1;
    }
    __syncthreads();
    if (tid < 64) {
        int v = h[tid];
        int s = v;
        #pragma unroll
        for (int off = 1; off < 64; off <<= 1) {
            int t = __shfl_up(s, off);
            if (tid >= off) s += t;
        }
        base_[tid] = s - v;
        h[tid] = 0;
    }
    __syncthreads();
    #pragma unroll
    for (int j = 0; j < 4; ++j) {
        if (bin[j] >= 0) {
            int n = n0 + tid + j * 256;
            int pos = n0 + base_[bin[j]] + atomicAdd(&h[bin[j]], 1);
            perm[vr * NN + pos] = n;
            iperm[vr * NN + n] = pos;
        }
    }
}

// ---------------- translate col_idx in place through iperm of the src side ----------------
__global__ __launch_bounds__(256) void translate_kernel(
    const int* __restrict__ iperm, int* __restrict__ col_idx)
{
    const int srcSide[NR] = {0, 1, 0, 1, 0, 1};   // A=0, B=1
    int r = blockIdx.y;
    const int* ip = iperm + srcSide[r] * NN;
    int* ci = col_idx + (size_t)r * EE;
    for (int e = blockIdx.x * 256 + threadIdx.x; e < EE; e += gridDim.x * 256)
        ci[e] = ip[ci[e]];
}

// ---------------- embeddings -> bf16, stored in permuted (processing) order ----------------
__global__ __launch_bounds__(256) void cvtp_kernel(
    const float* __restrict__ inA, const float* __restrict__ inB,
    const int* __restrict__ perm, ushort* __restrict__ outA, ushort* __restrict__ outB)
{
    int side = blockIdx.y;
    int t = blockIdx.x * 256 + threadIdx.x;
    if (t >= NN * 8) return;
    int idx = t >> 3, j = t & 7;
    int n = perm[side * NN + idx];
    const float* in = side ? inB : inA;
    ushort* out = side ? outB : outA;
    float4 v0 = ((const float4*)in)[n * 16 + j * 2];
    float4 v1 = ((const float4*)in)[n * 16 + j * 2 + 1];
    int4 o;
    o.x = (int)((unsigned int)f2bf(v0.x) | ((unsigned int)f2bf(v0.y) << 16));
    o.y = (int)((unsigned int)f2bf(v0.z) | ((unsigned int)f2bf(v0.w) << 16));
    o.z = (int)((unsigned int)f2bf(v1.x) | ((unsigned int)f2bf(v1.y) << 16));
    o.w = (int)((unsigned int)f2bf(v1.z) | ((unsigned int)f2bf(v1.w) << 16));
    *(int4*)(out + (size_t)idx * DD + j * 8) = o;
}

// ---------------- fused layer-0: gather 3 rels + bias + relu -> h0p (sequential write) ----------------
__global__ __launch_bounds__(256) void layer0_kernel(
    const ushort* __restrict__ eA, const ushort* __restrict__ eB,
    const int* __restrict__ row_ptr, const int* __restrict__ col_idx,
    const float* __restrict__ inv_deg, const int* __restrict__ perm,
    const float* __restrict__ bias, ushort* __restrict__ hA, ushort* __restrict__ hB)
{
    int side = blockIdx.y;
    const int relT[2][3] = { {1, 2, 5}, {0, 3, 4} };
    int tid = threadIdx.x;
    int wid = tid >> 6, lane = tid & 63;
    int grp = lane >> 3, sub = lane & 7;
    int idx = blockIdx.x * 32 + wid * 8 + grp;
    bool valid = (idx < NN);
    int n = valid ? perm[side * NN + idx] : 0;
    float acc[8];
    {
        float4 b0 = *(const float4*)(bias + sub * 8);
        float4 b1 = *(const float4*)(bias + sub * 8 + 4);
        acc[0] = b0.x; acc[1] = b0.y; acc[2] = b0.z; acc[3] = b0.w;
        acc[4] = b1.x; acc[5] = b1.y; acc[6] = b1.z; acc[7] = b1.w;
    }
    #pragma unroll
    for (int ks = 0; ks < 3; ++ks) {
        int r = relT[side][ks];
        const ushort* F = ((side == 0) == (ks == 1)) ? eA : eB;
        const int* rp = row_ptr + r * (NN + 1);
        const int* ci = col_idx + (size_t)r * EE;
        int s = valid ? rp[n] : 0;
        int e = valid ? rp[n + 1] : 0;
        float a[8] = {0.f, 0.f, 0.f, 0.f, 0.f, 0.f, 0.f, 0.f};
        gatherrow(F, ci, s, e, sub, a);
        float inv = valid ? inv_deg[r * NN + n] : 0.f;
        #pragma unroll
        for (int j = 0; j < 8; ++j) acc[j] += a[j] * inv;
    }
    if (valid) {
        ushort* h = side ? hB : hA;
        int4 o;
        o.x = (int)((unsigned int)f2bf(fmaxf(acc[0], 0.f)) | ((unsigned int)f2bf(fmaxf(acc[1], 0.f)) << 16));
        o.y = (int)((unsigned int)f2bf(fmaxf(acc[2], 0.f)) | ((unsigned int)f2bf(fmaxf(acc[3], 0.f)) << 16));
        o.z = (int)((unsigned int)f2bf(fmaxf(acc[4], 0.f)) | ((unsigned int)f2bf(fmaxf(acc[5], 0.f)) << 16));
        o.w = (int)((unsigned int)f2bf(fmaxf(acc[6], 0.f)) | ((unsigned int)f2bf(fmaxf(acc[7], 0.f)) << 16));
        *(int4*)(h + (size_t)idx * DD + sub * 8) = o;     // sequential by idx
    }
}

// ---------------- fused layer-1: gather -> LDS -> MFMA(h1) -> MFMA(y2 = h1 @ W2) -> y2 tables ----------------
// y2 slot tables (indexed in src-side permuted idx space): slot0 = h1B@W2[1], slot1 = h1A@W2[2], slot2 = h1B@W2[5]
__global__ __launch_bounds__(256) void layer1_fused_kernel(
    const ushort* __restrict__ h0A, const ushort* __restrict__ h0B,
    const int* __restrict__ row_ptr, const int* __restrict__ col_idx,
    const float* __restrict__ inv_deg, const int* __restrict__ perm,
    const ushort* __restrict__ Wp, const ushort* __restrict__ Wp2,
    const float* __restrict__ bias, ushort* __restrict__ y2)
{
    __shared__ unsigned int sZ[32 * LROW];   // 12.8 KB; reused as bf16 C-stage
    int side = blockIdx.y;
    const int relT[2][3] = { {1, 2, 5}, {0, 3, 4} };
    int tid = threadIdx.x;
    int wid = tid >> 6, lane = tid & 63;
    int grp = lane >> 3, sub = lane & 7;
    int ln = wid * 8 + grp;
    int idx0 = blockIdx.x * 32;
    int idx = idx0 + ln;
    bool valid = (idx < NN);
    int n = valid ? perm[side * NN + idx] : 0;
    #pragma unroll
    for (int ks = 0; ks < 3; ++ks) {
        int r = relT[side][ks];
        const ushort* F = ((side == 0) == (ks == 1)) ? h0A : h0B;
        const int* rp = row_ptr + r * (NN + 1);
        const int* ci = col_idx + (size_t)r * EE;
        int s = valid ? rp[n] : 0;
        int e = valid ? rp[n + 1] : 0;
        float a[8] = {0.f, 0.f, 0.f, 0.f, 0.f, 0.f, 0.f, 0.f};
        gatherrow(F, ci, s, e, sub, a);
        float inv = valid ? inv_deg[r * NN + n] : 0.f;
        int4 o;
        o.x = (int)((unsigned int)f2bf(a[0] * inv) | ((unsigned int)f2bf(a[1] * inv) << 16));
        o.y = (int)((unsigned int)f2bf(a[2] * inv) | ((unsigned int)f2bf(a[3] * inv) << 16));
        o.z = (int)((unsigned int)f2bf(a[4] * inv) | ((unsigned int)f2bf(a[5] * inv) << 16));
        o.w = (int)((unsigned int)f2bf(a[6] * inv) | ((unsigned int)f2bf(a[7] * inv) << 16));
        *(int4*)&sZ[ln * LROW + ks * 32 + sub * 4] = o;
    }
    __syncthreads();
    // MFMA 1: h1 rows. wave -> 16 rows x 32 cols
    int q = lane & 15, p = lane >> 4;
    int base16 = (wid >> 1) * 16, cb = (wid & 1) * 32;
    f32x4 acc0 = {0.f, 0.f, 0.f, 0.f};
    f32x4 acc1 = {0.f, 0.f, 0.f, 0.f};
    #pragma unroll
    for (int ks = 0; ks < 3; ++ks) {
        int rel = relT[side][ks];
        #pragma unroll
        for (int tt = 0; tt < 2; ++tt) {
            int4 t4 = *(const int4*)&sZ[(base16 + q) * LROW + (ks * 2 + tt) * 16 + p * 4];
            bf16x8 a = *(const bf16x8*)&t4;
            const ushort* wb = Wp + (((size_t)(rel * 8 + tt * 4 + p) * 64 + cb + q) << 3);
            bf16x8 b0 = *(const bf16x8*)wb;
            bf16x8 b1 = *(const bf16x8*)(wb + 16 * 8);
            acc0 = __builtin_amdgcn_mfma_f32_16x16x32_bf16(a, b0, acc0, 0, 0, 0);
            acc1 = __builtin_amdgcn_mfma_f32_16x16x32_bf16(a, b1, acc1, 0, 0, 0);
        }
    }
    __syncthreads();
    ushort* sC = (ushort*)sZ;
    {
        float bv0 = bias[cb + q], bv1 = bias[cb + 16 + q];
        #pragma unroll
        for (int v = 0; v < 4; ++v) {
            int row = base16 + p * 4 + v;
            sC[row * 64 + cb + q]      = f2bf(fmaxf(acc0[v] + bv0, 0.f));
            sC[row * 64 + cb + 16 + q] = f2bf(fmaxf(acc1[v] + bv1, 0.f));
        }
    }
    __syncthreads();
    // MFMA 2: y2 = h1(sC rows) @ W2_rel -> global y2 slot tables (h1 itself never hits global)
    // side 0 (h1A): slot1/rel2, waves 0-1. side 1 (h1B): slot0/rel1 waves 0-1, slot2/rel5 waves 2-3.
    int yb16, rel2_, slot;
    bool doy;
    if (side == 0) { doy = (wid < 2); yb16 = wid * 16;        rel2_ = 2;                    slot = 1; }
    else           { doy = true;      yb16 = (wid & 1) * 16;  rel2_ = (wid >> 1) ? 5 : 1;   slot = (wid >> 1) ? 2 : 0; }
    if (doy) {
        f32x4 yacc = {0.f, 0.f, 0.f, 0.f};
        #pragma unroll
        for (int tt = 0; tt < 2; ++tt) {
            bf16x8 a = *(const bf16x8*)(sC + (yb16 + q) * 64 + tt * 32 + p * 8);
            bf16x8 b = *(const bf16x8*)(Wp2 + (((size_t)(rel2_ * 8 + tt * 4 + p) * 16 + q) << 3));
            yacc = __builtin_amdgcn_mfma_f32_16x16x32_bf16(a, b, yacc, 0, 0, 0);
        }
        ushort* Y = y2 + (size_t)slot * NN * OD;
        #pragma unroll
        for (int v = 0; v < 4; ++v) {
            int row = yb16 + p * 4 + v;
            if (idx0 + row < NN) Y[(size_t)(idx0 + row) * OD + q] = f2bf(yacc[v]);
        }
    }
}

// ---------------- layer-2: light 32B/edge gather from y2 tables + bias -> d_out (f32) ----------------
__global__ __launch_bounds__(256) void layer2_gather_kernel(
    const ushort* __restrict__ y2,
    const int* __restrict__ row_ptr, const int* __restrict__ col_idx,
    const float* __restrict__ inv_deg, const int* __restrict__ perm,
    const float* __restrict__ bias, float* __restrict__ out)
{
    const int rr0 = 1, rr1 = 2, rr2 = 5;
    const ushort* Y0 = y2;
    const ushort* Y1 = y2 + (size_t)NN * OD;
    const ushort* Y2 = y2 + (size_t)2 * NN * OD;
    int tid = threadIdx.x;
    int wid = tid >> 6, lane = tid & 63;
    int grp = lane >> 3, sub = lane & 7;
    int idx = blockIdx.x * 32 + wid * 8 + grp;
    if (idx >= NN) return;
    int n = perm[idx];
    float o0 = 0.f, o1 = 0.f;
    #pragma unroll
    for (int ks = 0; ks < 3; ++ks) {
        int r = (ks == 0) ? rr0 : ((ks == 1) ? rr1 : rr2);
        const ushort* Y = (ks == 0) ? Y0 : ((ks == 1) ? Y1 : Y2);
        const int* rp = row_ptr + r * (NN + 1);
        const int* ci = col_idx + (size_t)r * EE;
        int s = rp[n], e = rp[n + 1];
        float a0 = 0.f, a1 = 0.f;
        int t = s;
        for (; t + 4 <= e; t += 4) {
            unsigned int u0 = *(const unsigned int*)(Y + (size_t)ci[t] * OD + sub * 2);
            unsigned int u1 = *(const unsigned int*)(Y + (size_t)ci[t + 1] * OD + sub * 2);
            unsigned int u2 = *(const unsigned int*)(Y + (size_t)ci[t + 2] * OD + sub * 2);
            unsigned int u3 = *(const unsigned int*)(Y + (size_t)ci[t + 3] * OD + sub * 2);
            float l, h;
            bfpair(u0, l, h); a0 += l; a1 += h;
            bfpair(u1, l, h); a0 += l; a1 += h;
            bfpair(u2, l, h); a0 += l; a1 += h;
            bfpair(u3, l, h); a0 += l; a1 += h;
        }
        for (; t < e; ++t) {
            unsigned int u = *(const unsigned int*)(Y + (size_t)ci[t] * OD + sub * 2);
            float l, h;
            bfpair(u, l, h); a0 += l; a1 += h;
        }
        float inv = inv_deg[r * NN + n];
        o0 += a0 * inv; o1 += a1 * inv;
    }
    float2 ov;
    ov.x = o0 + bias[sub * 2];
    ov.y = o1 + bias[sub * 2 + 1];
    *(float2*)(out + (size_t)n * OD + sub * 2) = ov;
}

extern "C" void kernel_launch(void* const* d_in, const int* in_sizes, int n_in,
                              void* d_out, int out_size, void* d_ws, size_t ws_size,
                              hipStream_t stream)
{
    const float* embA  = (const float*)d_in[0];
    const float* embB  = (const float*)d_in[1];
    const float* bias0 = (const float*)d_in[2];
    const float* wc1   = (const float*)d_in[3];
    const float* b1    = (const float*)d_in[4];
    const float* bias1 = (const float*)d_in[5];
    const float* wc2   = (const float*)d_in[6];
    const float* b2    = (const float*)d_in[7];
    const float* bias2 = (const float*)d_in[8];

    Edges ep;
    for (int r = 0; r < NR; ++r) {
        ep.src[r] = (const int*)d_in[9 + 2 * r];
        ep.dst[r] = (const int*)d_in[10 + 2 * r];
    }

    char* ws = (char*)d_ws;
    size_t off = 0;
    auto alloc = [&](size_t bytes) {
        void* p = ws + off;
        off = (off + bytes + 255) & ~(size_t)255;
        return p;
    };
    ushort* Wp1     = (ushort*)alloc((size_t)NR * 8 * 64 * 8 * 2);
    ushort* Wp2     = (ushort*)alloc((size_t)NR * 8 * 16 * 8 * 2);
    int*    cnt_mat = (int*)   alloc((size_t)NR * FLATN * 4);
    int*    off_fl  = (int*)   alloc((size_t)NR * FLATN * 4);
    int*    bbase   = (int*)   alloc((size_t)NR * (NBK + 1) * 4);
    int*    row_ptr = (int*)   alloc((size_t)NR * (NN + 1) * 4);
    float*  inv_deg = (float*) alloc((size_t)NR * NN * 4);
    int*    col_idx = (int*)   alloc((size_t)NR * EE * 4);
    int*    perm    = (int*)   alloc((size_t)2 * NN * 4);
    int*    iperm   = (int*)   alloc((size_t)2 * NN * 4);
    ushort* reg1    = (ushort*)alloc((size_t)2 * NN * DD * 2);   // ebuf -> embp -> y2
    ushort* h0pA    = (ushort*)alloc((size_t)NN * DD * 2);
    ushort* h0pB    = (ushort*)alloc((size_t)NN * DD * 2);
    (void)ws_size;

    // lifetime-disjoint aliases inside reg1 (25.6 MB):
    unsigned int* ebuf  = (unsigned int*)reg1;       // dead after csr_fine
    ushort*       embpA = reg1;                      // written by cvtp (after csr_fine), dead after layer0
    ushort*       embpB = reg1 + (size_t)NN * DD;
    ushort*       y2buf = reg1;                      // 3 * NN * 16 * 2B = 9.6 MB, written by layer1

    int nw = NR * DD * DD + NR * DD * OD;
    build_w_kernel<<<(nw + 255) / 256, 256, 0, stream>>>(wc1, b1, wc2, b2, Wp1, Wp2);

    count_kernel<<<dim3(SBLK, NR), 256, 0, stream>>>(ep, cnt_mat);
    flat_scan_kernel<<<NR, 1024, 0, stream>>>(cnt_mat, off_fl, bbase);
    scatter2_kernel<<<dim3(SBLK, NR), 256, 0, stream>>>(ep, off_fl, ebuf);
    csr_fine_kernel<<<dim3(NBK, NR), 256, 0, stream>>>(ebuf, bbase, row_ptr, inv_deg, col_idx);

    bsort_kernel<<<dim3(NBK, 2), 256, 0, stream>>>(row_ptr, perm, iperm);
    translate_kernel<<<dim3(64, NR), 256, 0, stream>>>(iperm, col_idx);
    cvtp_kernel<<<dim3((NN * 8 + 255) / 256, 2), 256, 0, stream>>>(
        embA, embB, perm, embpA, embpB);

    int agx = (NN + 31) / 32;
    // relations: r0 A->B, r1 B->A, r2 A->A, r3 B->B, r4 A->B, r5 B->A
    // dst A: rels {1,2,5} srcs {B,A,B};  dst B: rels {0,3,4} srcs {A,B,A}

    layer0_kernel<<<dim3(agx, 2), 256, 0, stream>>>(
        embpA, embpB, row_ptr, col_idx, inv_deg, perm, bias0, h0pA, h0pB);

    layer1_fused_kernel<<<dim3(agx, 2), 256, 0, stream>>>(
        h0pA, h0pB, row_ptr, col_idx, inv_deg, perm, Wp1, Wp2, bias1, y2buf);

    layer2_gather_kernel<<<agx, 256, 0, stream>>>(
        y2buf, row_ptr, col_idx, inv_deg, perm, bias2, (float*)d_out);
}